// Round 1
// baseline (68.974 us; speedup 1.0000x reference)
//
#include <hip/hip_runtime.h>

#define THREADS 256
#define WORKERS 243   // 3 puzzles x 81 cells

__global__ __launch_bounds__(THREADS) void sudoku_main(
    const float* __restrict__ logits,
    const int*   __restrict__ targets,
    const int*   __restrict__ puzzles,
    float* __restrict__ acc,
    int B, int numTriples)
{
  __shared__ float sprob[3 * 81 * 9];   // masked probs for 3 puzzles
  __shared__ float sred[4][5];          // cross-wave reduction scratch

  const int tid    = threadIdx.x;
  const bool worker = tid < WORKERS;
  const int lp   = tid / 81;    // local puzzle 0..2 (phase A)
  const int cell = tid % 81;    // cell 0..80 (g1*9+g2)

  // Constraint-phase mapping: same 243 threads reinterpreted as
  // (unit_type, unit_index, channel); each handles all 3 local puzzles.
  const int ut   = lp;          // 0=row, 1=col, 2=box
  const int uidx = cell / 9;
  const int uch  = cell % 9;
  int ucell[9];
#pragma unroll
  for (int j = 0; j < 9; ++j) {
    if (ut == 0)      ucell[j] = uidx * 9 + j;                       // row: sum over axis 2
    else if (ut == 1) ucell[j] = j * 9 + uidx;                       // col: sum over axis 1
    else              ucell[j] = (uidx / 3) * 27 + (uidx % 3) * 3    // 3x3 box
                                  + (j / 3) * 9 + (j % 3);
  }

  float a_focal = 0.f, a_ent = 0.f, a_msk = 0.f, a_uniq = 0.f, a_sq = 0.f;

  for (int t = blockIdx.x; t < numTriples; t += gridDim.x) {
    const int p = t * 3 + lp;
    const bool valid = worker && (p < B);
    if (worker) {
      if (valid) {
        const size_t cidx = (size_t)p * 81 + cell;
        const float* Lp = logits + cidx * 9;
        float l[9];
#pragma unroll
        for (int i = 0; i < 9; ++i) l[i] = Lp[i];
        float m = l[0];
#pragma unroll
        for (int i = 1; i < 9; ++i) m = fmaxf(m, l[i]);
        float e[9], s = 0.f, lsum = 0.f, e1 = -1.f, e2 = -1.f;
#pragma unroll
        for (int i = 0; i < 9; ++i) {
          float x  = l[i] - m;
          float ei = __expf(x);
          e[i] = ei;
          s += ei;
          lsum += ei * x;
          if (ei > e1) { e2 = e1; e1 = ei; }
          else if (ei > e2) { e2 = ei; }
        }
        float inv_s = 1.f / s;
        float logs  = __logf(s);

        int tg = targets[cidx] - 1;
        tg = tg < 0 ? 0 : (tg > 8 ? 8 : tg);
        float lpt   = (l[tg] - m) - logs;       // log p_target
        float pt    = e[tg] * inv_s;
        float om    = 1.f - pt;
        float focal = om * om * (-lpt);

        float ent = logs - lsum * inv_s;        // -(sum p*logp)
        float gap = (e1 - e2) * inv_s;          // top1 - top2 prob
        float uq  = fmaxf(0.f, 1.f - gap);

        float mk = (puzzles[cidx] == 0) ? 1.f : 0.f;
        a_focal += focal * mk;
        a_ent   += ent * mk;
        a_msk   += mk;
        a_uniq  += uq;                          // uniqueness is unmasked

        float pm = inv_s * mk;
#pragma unroll
        for (int i = 0; i < 9; ++i) sprob[tid * 9 + i] = e[i] * pm;
      } else {
#pragma unroll
        for (int i = 0; i < 9; ++i) sprob[tid * 9 + i] = 0.f;
      }
    }
    __syncthreads();
    if (worker) {
#pragma unroll
      for (int k = 0; k < 3; ++k) {
        if (t * 3 + k < B) {
          float s = 0.f;
#pragma unroll
          for (int j = 0; j < 9; ++j)
            s += sprob[(k * 81 + ucell[j]) * 9 + uch];
          float d = s - 1.f;
          a_sq += d * d;
        }
      }
    }
    __syncthreads();
  }

  // wave (64-lane) reduction of the 5 accumulators
#pragma unroll
  for (int off = 32; off > 0; off >>= 1) {
    a_focal += __shfl_down(a_focal, off);
    a_ent   += __shfl_down(a_ent,   off);
    a_msk   += __shfl_down(a_msk,   off);
    a_uniq  += __shfl_down(a_uniq,  off);
    a_sq    += __shfl_down(a_sq,    off);
  }
  const int wave = tid >> 6;
  if ((tid & 63) == 0) {
    sred[wave][0] = a_focal; sred[wave][1] = a_ent; sred[wave][2] = a_msk;
    sred[wave][3] = a_uniq;  sred[wave][4] = a_sq;
  }
  __syncthreads();
  if (tid < 5) {
    float v = sred[0][tid] + sred[1][tid] + sred[2][tid] + sred[3][tid];
    atomicAdd(&acc[tid], v);
  }
}

__global__ void sudoku_finalize(const float* __restrict__ acc,
                                float* __restrict__ out, float invBG)
{
  float focal = acc[0], ent = acc[1], msum = acc[2], uniq = acc[3], sq = acc[4];
  float inv_m = 1.f / (msum + 1e-8f);
  float ce    = focal * inv_m;
  float entl  = 0.1f * ent * inv_m;
  float uql   = 0.1f * uniq * invBG;
  float rcb   = sq * invBG;   // (row+col+box) means share denominator B*81
  float constraint = (rcb + entl + uql) * 0.2f;
  out[0] = ce + 0.5f * constraint;
}

extern "C" void kernel_launch(void* const* d_in, const int* in_sizes, int n_in,
                              void* d_out, int out_size, void* d_ws, size_t ws_size,
                              hipStream_t stream)
{
  (void)n_in; (void)out_size; (void)ws_size;
  const float* logits  = (const float*)d_in[0];
  const int*   targets = (const int*)d_in[1];
  const int*   puzzles = (const int*)d_in[2];
  float* out = (float*)d_out;
  float* acc = (float*)d_ws;

  const int B = in_sizes[0] / 729;          // B*9*9*9 logits
  const int numTriples = (B + 2) / 3;

  hipMemsetAsync(acc, 0, 5 * sizeof(float), stream);

  int grid = numTriples < 2048 ? numTriples : 2048;
  sudoku_main<<<grid, THREADS, 0, stream>>>(logits, targets, puzzles, acc, B, numTriples);

  const float invBG = 1.f / ((float)B * 81.f);
  sudoku_finalize<<<1, 1, 0, stream>>>(acc, out, invBG);
}